// Round 1
// 312.693 us; speedup vs baseline: 1.0080x; 1.0080x over previous
//
#include <hip/hip_runtime.h>

typedef short v8s __attribute__((ext_vector_type(8)));
typedef float v4f __attribute__((ext_vector_type(4)));
using u16 = unsigned short;

__device__ __forceinline__ u16 f2b(float f) {
  union { float f; unsigned u; } v; v.f = f;
  unsigned r = v.u + 0x7FFFu + ((v.u >> 16) & 1u);
  return (u16)(r >> 16);
}

// ---------------- LayerNorm + bf16 casts ----------------
__global__ void ln_prep(const float* __restrict__ x, const float* __restrict__ ctx,
                        const float* __restrict__ gamma, const float* __restrict__ beta,
                        float* __restrict__ xn_f, u16* __restrict__ xn_b,
                        u16* __restrict__ ctx_b)
{
  const int tid = threadIdx.x;
  if (blockIdx.y == 0) {
    const int wid = tid >> 6, lane = tid & 63;
    const int row = blockIdx.x * 4 + wid;
    const float4 xv = *(const float4*)(x + (size_t)row * 256 + lane * 4);
    float s1 = xv.x + xv.y + xv.z + xv.w;
    float s2 = xv.x*xv.x + xv.y*xv.y + xv.z*xv.z + xv.w*xv.w;
#pragma unroll
    for (int m = 32; m >= 1; m >>= 1) {
      s1 += __shfl_xor(s1, m);
      s2 += __shfl_xor(s2, m);
    }
    const float mu  = s1 * (1.0f/256.0f);
    const float var = s2 * (1.0f/256.0f) - mu*mu;
    const float rs  = rsqrtf(var + 1e-3f);
    const float4 g = *(const float4*)(gamma + lane*4);
    const float4 b = *(const float4*)(beta  + lane*4);
    float4 y;
    y.x = (xv.x-mu)*rs*g.x + b.x;
    y.y = (xv.y-mu)*rs*g.y + b.y;
    y.z = (xv.z-mu)*rs*g.z + b.z;
    y.w = (xv.w-mu)*rs*g.w + b.w;
    *(float4*)(xn_f + (size_t)row*256 + lane*4) = y;
    ushort4 yb; yb.x=f2b(y.x); yb.y=f2b(y.y); yb.z=f2b(y.z); yb.w=f2b(y.w);
    *(ushort4*)(xn_b + (size_t)row*256 + lane*4) = yb;
  } else {
    const size_t idx = (size_t)blockIdx.x * 1024 + (size_t)tid * 4;
    const float4 cv = *(const float4*)(ctx + idx);
    ushort4 cb; cb.x=f2b(cv.x); cb.y=f2b(cv.y); cb.z=f2b(cv.z); cb.w=f2b(cv.w);
    *(ushort4*)(ctx_b + idx) = cb;
  }
}

// ---------------- weight transpose + bf16 cast ----------------
__global__ void wtrans(const float* __restrict__ wq, const float* __restrict__ wk,
                       const float* __restrict__ wv, const float* __restrict__ wp,
                       u16* __restrict__ tq, u16* __restrict__ tk,
                       u16* __restrict__ tv, u16* __restrict__ tp)
{
  const float* src; u16* dst;
  switch (blockIdx.y) {
    case 0:  src = wq; dst = tq; break;
    case 1:  src = wk; dst = tk; break;
    case 2:  src = wv; dst = tv; break;
    default: src = wp; dst = tp; break;
  }
  const int t  = threadIdx.x;
  const int kk = blockIdx.x * 16 + (t >> 4);
  const int n0 = (t & 15) * 16;
#pragma unroll
  for (int j = 0; j < 16; j++)
    dst[(size_t)(n0 + j) * 256 + kk] = f2b(src[(size_t)kk * 256 + n0 + j]);
}

// ---------------- q/k/v GEMM ----------------
__global__ __launch_bounds__(256) void gemm_qkv(
    const u16* __restrict__ xn_b, const u16* __restrict__ ctx_b,
    const u16* __restrict__ wqt, const u16* __restrict__ wkt, const u16* __restrict__ wvt,
    const float* __restrict__ bq, const float* __restrict__ bk, const float* __restrict__ bv,
    u16* __restrict__ qo, u16* __restrict__ ko, u16* __restrict__ vto)
{
  const int mode = blockIdx.y;
  const u16* A; const u16* Wt; const float* bias;
  if (mode == 0)      { A = xn_b;  Wt = wqt; bias = bq; }
  else if (mode == 1) { A = ctx_b; Wt = wkt; bias = bk; }
  else                { A = ctx_b; Wt = wvt; bias = bv; }
  const int wid = threadIdx.x >> 6, lane = threadIdx.x & 63;
  const int lm = lane & 15, q4 = lane >> 4;
  const int m0 = blockIdx.x * 64 + wid * 16;
  const u16* arow = A + (size_t)(m0 + lm) * 256 + q4 * 8;
  v8s af[8];
#pragma unroll
  for (int kf = 0; kf < 8; kf++) af[kf] = *(const v8s*)(arow + kf * 32);
#pragma unroll
  for (int ct = 0; ct < 16; ct++) {
    const int c = ct * 16 + lm;
    const u16* wrow = Wt + (size_t)c * 256 + q4 * 8;
    v4f acc = {0.f, 0.f, 0.f, 0.f};
#pragma unroll
    for (int kf = 0; kf < 8; kf++)
      acc = __builtin_amdgcn_mfma_f32_16x16x32_bf16(af[kf], *(const v8s*)(wrow + kf * 32), acc, 0, 0, 0);
    const float bb = bias[c];
    if (mode == 2) {
      const int b = m0 >> 12;
      const int s = (m0 & 4095) + q4 * 4;
      ushort4 pk;
      pk.x = f2b(acc[0] + bb); pk.y = f2b(acc[1] + bb);
      pk.z = f2b(acc[2] + bb); pk.w = f2b(acc[3] + bb);
      *(ushort4*)(vto + (size_t)b * 1048576 + (size_t)c * 4096 + s) = pk;
    } else {
      u16* out = (mode == 0) ? qo : ko;
#pragma unroll
      for (int r = 0; r < 4; r++)
        out[(size_t)(m0 + q4 * 4 + r) * 256 + c] = f2b(acc[r] + bb);
    }
  }
}

// ---------------- flash-style attention, v4 (software-pipelined) ----------------
// Block = 64 Q rows, 4 waves, 1 wave/SIMD. Per 64-key chunk n, one iteration does:
//   phase A(n):  S^T strips via mfma(K, Q) -> per lane 4 CONSECUTIVE keys of one
//                q-row -> exp2 -> v_cvt_pk_bf16 -> ONE ds_write_b64 per q-tile
//   phase B(n-1): O += P[(n-1)&1] * V  (independent of A(n) -> compiler interleaves)
//   issue K(n+1), V(n) global loads (consumed next iteration, ~full chunk of cover)
//   s_waitcnt lgkmcnt(0) + RAW s_barrier  (NO vmcnt drain: prefetches stay in flight)
// Buffer discipline: iter n writes P[n&1], reads P[(n-1)&1]; the overwrite of
// P[(n+1)&1] (iter n+1) vs its readers (iter n-1... B(n-2)? no: B(n-1) in iter n)
// is separated by the end-of-iteration barrier. One barrier per chunk.
__global__ __launch_bounds__(256, 1) void attn_kernel(
    const u16* __restrict__ q, const u16* __restrict__ k,
    const u16* __restrict__ vt, u16* __restrict__ ao)
{
  __shared__ u16 P[2][64][72];   // [buf][q][key] bf16, 18.4 KB
  __shared__ float Lp[4][64];
  __shared__ float Lt[64];
  const int b   = blockIdx.y;
  const int tid = threadIdx.x;
  const int w   = tid >> 6, lane = tid & 63;
  const int lm  = lane & 15, q4 = lane >> 4;
  const int m0  = blockIdx.x * 64;
  const u16* qb = q  + (size_t)b * 4096 * 256;
  const u16* kb = k  + (size_t)b * 4096 * 256;
  const u16* vb = vt + (size_t)b * 256 * 4096;

  // Q fragments for 4 q-tiles (held all kernel): qf[qt][kf]
  v8s qf[4][8];
#pragma unroll
  for (int qt = 0; qt < 4; qt++) {
    const u16* qrow = qb + (size_t)(m0 + qt * 16 + lm) * 256 + q4 * 8;
#pragma unroll
    for (int kf = 0; kf < 8; kf++) qf[qt][kf] = *(const v8s*)(qrow + kf * 32);
  }

  v4f o[4][4];
#pragma unroll
  for (int qt = 0; qt < 4; qt++)
#pragma unroll
    for (int ct = 0; ct < 4; ct++) o[qt][ct] = (v4f){0.f, 0.f, 0.f, 0.f};
  float lsum[4] = {0.f, 0.f, 0.f, 0.f};

  // K fragments for chunk 0; V fragments filled at end of each iteration.
  v8s kfr[8], vfr[4][2];
  {
    const u16* krow = kb + (size_t)(w * 16 + lm) * 256 + q4 * 8;
#pragma unroll
    for (int kf = 0; kf < 8; kf++) kfr[kf] = *(const v8s*)(krow + kf * 32);
  }

// One pipelined chunk. PW_/PR_/DOB_ are compile-time constants.
#define ATTN_BODY(S0_, PW_, PR_, DOB_)                                           \
  do {                                                                           \
    const int s0_ = (S0_);                                                       \
    /* phase A: S^T = mfma(K, Q): lane -> q-row = qt*16+lm, keys w*16+q4*4+r */  \
    v4f sc_[4];                                                                  \
    _Pragma("unroll")                                                            \
    for (int qt = 0; qt < 4; qt++) sc_[qt] = (v4f){0.f, 0.f, 0.f, 0.f};          \
    _Pragma("unroll")                                                            \
    for (int kf = 0; kf < 8; kf++)                                               \
      _Pragma("unroll")                                                          \
      for (int qt = 0; qt < 4; qt++)                                             \
        sc_[qt] = __builtin_amdgcn_mfma_f32_16x16x32_bf16(kfr[kf], qf[qt][kf],   \
                                                          sc_[qt], 0, 0, 0);     \
    /* issue K(next chunk) into kfr (WAR on regs: loads issue after A reads) */  \
    {                                                                            \
      const int sn_ = (s0_ + 64) & 4095;                                         \
      const u16* krn_ = kb + (size_t)(sn_ + w * 16 + lm) * 256 + q4 * 8;         \
      _Pragma("unroll")                                                          \
      for (int kf = 0; kf < 8; kf++) kfr[kf] = *(const v8s*)(krn_ + kf * 32);    \
    }                                                                            \
    /* exp2 (folded scale) -> cvt_pk bf16 pairs -> one b64 write per q-tile */   \
    _Pragma("unroll")                                                            \
    for (int qt = 0; qt < 4; qt++) {                                             \
      const float e0_ = exp2f(sc_[qt][0] * 0.09016844f);                         \
      const float e1_ = exp2f(sc_[qt][1] * 0.09016844f);                         \
      const float e2_ = exp2f(sc_[qt][2] * 0.09016844f);                         \
      const float e3_ = exp2f(sc_[qt][3] * 0.09016844f);                         \
      lsum[qt] += (e0_ + e1_) + (e2_ + e3_);                                     \
      unsigned d0_, d1_;                                                         \
      asm("v_cvt_pk_bf16_f32 %0, %1, %2" : "=v"(d0_) : "v"(e0_), "v"(e1_));      \
      asm("v_cvt_pk_bf16_f32 %0, %1, %2" : "=v"(d1_) : "v"(e2_), "v"(e3_));      \
      uint2 pk_; pk_.x = d0_; pk_.y = d1_;                                       \
      *(uint2*)(&P[PW_][qt * 16 + lm][w * 16 + q4 * 4]) = pk_;                   \
    }                                                                            \
    /* phase B(prev chunk): independent of A -> interleaves on the MFMA pipe */  \
    if (DOB_) {                                                                  \
      _Pragma("unroll")                                                          \
      for (int qt = 0; qt < 4; qt++) {                                           \
        const v8s pf0_ = *(const v8s*)(&P[PR_][qt * 16 + lm][q4 * 8]);           \
        const v8s pf1_ = *(const v8s*)(&P[PR_][qt * 16 + lm][32 + q4 * 8]);      \
        _Pragma("unroll")                                                        \
        for (int ct = 0; ct < 4; ct++) {                                         \
          o[qt][ct] = __builtin_amdgcn_mfma_f32_16x16x32_bf16(                   \
              pf0_, vfr[ct][0], o[qt][ct], 0, 0, 0);                             \
          o[qt][ct] = __builtin_amdgcn_mfma_f32_16x16x32_bf16(                   \
              pf1_, vfr[ct][1], o[qt][ct], 0, 0, 0);                             \
        }                                                                        \
      }                                                                          \
    }                                                                            \
    /* issue V(this chunk), consumed by next iteration's phase B */              \
    _Pragma("unroll")                                                            \
    for (int ct = 0; ct < 4; ct++) {                                             \
      const u16* vrow_ =                                                         \
          vb + (size_t)(w * 64 + ct * 16 + lm) * 4096 + s0_ + q4 * 8;            \
      vfr[ct][0] = *(const v8s*)(vrow_);                                         \
      vfr[ct][1] = *(const v8s*)(vrow_ + 32);                                    \
    }                                                                            \
    /* LDS-visibility-only barrier: global prefetches stay in flight */          \
    asm volatile("s_waitcnt lgkmcnt(0)" ::: "memory");                           \
    __builtin_amdgcn_s_barrier();                                                \
    asm volatile("" ::: "memory");                                               \
  } while (0)

  // prologue chunk 0 (no phase B yet)
  ATTN_BODY(0, 0, 1, 0);
  // chunks 1..62 (parity pairs keep P indices compile-time)
#pragma unroll 1
  for (int n = 1; n < 63; n += 2) {
    ATTN_BODY(n << 6, 1, 0, 1);
    ATTN_BODY((n + 1) << 6, 0, 1, 1);
  }
  // chunk 63
  ATTN_BODY(63 << 6, 1, 0, 1);
#undef ATTN_BODY

  // epilogue: phase B for chunk 63 (P[1], vfr = V(63))
#pragma unroll
  for (int qt = 0; qt < 4; qt++) {
    const v8s pf0 = *(const v8s*)(&P[1][qt * 16 + lm][q4 * 8]);
    const v8s pf1 = *(const v8s*)(&P[1][qt * 16 + lm][32 + q4 * 8]);
#pragma unroll
    for (int ct = 0; ct < 4; ct++) {
      o[qt][ct] = __builtin_amdgcn_mfma_f32_16x16x32_bf16(pf0, vfr[ct][0], o[qt][ct], 0, 0, 0);
      o[qt][ct] = __builtin_amdgcn_mfma_f32_16x16x32_bf16(pf1, vfr[ct][1], o[qt][ct], 0, 0, 0);
    }
  }

  // l: per-lane lsum covers keys {w*16 + q4*4 + r} of q-row qt*16+lm.
  // Reduce across the four q4 groups (lanes lm, lm+16, lm+32, lm+48).
#pragma unroll
  for (int qt = 0; qt < 4; qt++) {
    float t = lsum[qt];
    t += __shfl_xor(t, 16);
    t += __shfl_xor(t, 32);
    lsum[qt] = t;
  }
  if (q4 == 0) {
#pragma unroll
    for (int qt = 0; qt < 4; qt++) Lp[w][qt * 16 + lm] = lsum[qt];
  }
  __syncthreads();
  if (tid < 64) Lt[tid] = Lp[0][tid] + Lp[1][tid] + Lp[2][tid] + Lp[3][tid];
  __syncthreads();

  u16* aob = ao + ((size_t)b * 4096 + m0) * 256;
#pragma unroll
  for (int qt = 0; qt < 4; qt++)
#pragma unroll
    for (int r = 0; r < 4; r++) {
      const float linv = 1.0f / Lt[qt * 16 + q4 * 4 + r];
#pragma unroll
      for (int ct = 0; ct < 4; ct++)
        aob[(size_t)(qt * 16 + q4 * 4 + r) * 256 + w * 64 + ct * 16 + lm] =
            f2b(o[qt][ct][r] * linv);
    }
}

// ---------------- proj GEMM + bias + residual ----------------
__global__ __launch_bounds__(256) void gemm_proj(
    const u16* __restrict__ A, const u16* __restrict__ Wt, const float* __restrict__ bias,
    const float* __restrict__ xn_f, float* __restrict__ out)
{
  const int wid = threadIdx.x >> 6, lane = threadIdx.x & 63;
  const int lm = lane & 15, q4 = lane >> 4;
  const int m0 = blockIdx.x * 64 + wid * 16;
  const u16* arow = A + (size_t)(m0 + lm) * 256 + q4 * 8;
  v8s af[8];
#pragma unroll
  for (int kf = 0; kf < 8; kf++) af[kf] = *(const v8s*)(arow + kf * 32);
#pragma unroll
  for (int ct = 0; ct < 16; ct++) {
    const int c = ct * 16 + lm;
    const u16* wrow = Wt + (size_t)c * 256 + q4 * 8;
    v4f acc = {0.f, 0.f, 0.f, 0.f};
#pragma unroll
    for (int kf = 0; kf < 8; kf++)
      acc = __builtin_amdgcn_mfma_f32_16x16x32_bf16(af[kf], *(const v8s*)(wrow + kf * 32), acc, 0, 0, 0);
    const float bb = bias[c];
#pragma unroll
    for (int r = 0; r < 4; r++) {
      const size_t idx = (size_t)(m0 + q4 * 4 + r) * 256 + c;
      out[idx] = xn_f[idx] + acc[r] + bb;
    }
  }
}

extern "C" void kernel_launch(void* const* d_in, const int* in_sizes, int n_in,
                              void* d_out, int out_size, void* d_ws, size_t ws_size,
                              hipStream_t stream)
{
  (void)in_sizes; (void)n_in; (void)out_size; (void)ws_size;
  const float* inputs  = (const float*)d_in[0];
  const float* context = (const float*)d_in[1];
  const float* Wq = (const float*)d_in[2];
  const float* bq = (const float*)d_in[3];
  const float* Wk = (const float*)d_in[4];
  const float* bk = (const float*)d_in[5];
  const float* Wv = (const float*)d_in[6];
  const float* bv = (const float*)d_in[7];
  const float* Wp = (const float*)d_in[8];
  const float* bp = (const float*)d_in[9];
  const float* gamma = (const float*)d_in[10];
  const float* beta  = (const float*)d_in[11];
  float* out = (float*)d_out;

  char* p = (char*)d_ws;
  float* xn_f = (float*)p; p += (size_t)16384 * 256 * 4;
  u16* xn_b   = (u16*)p;   p += (size_t)16384 * 256 * 2;
  u16* ctx_b  = (u16*)p;   p += (size_t)16384 * 256 * 2;
  u16* qbuf   = (u16*)p;   p += (size_t)16384 * 256 * 2;
  u16* kbuf   = (u16*)p;   p += (size_t)16384 * 256 * 2;
  u16* vtbuf  = (u16*)p;   p += (size_t)16384 * 256 * 2;
  u16* wqt = (u16*)p; p += (size_t)256 * 256 * 2;
  u16* wkt = (u16*)p; p += (size_t)256 * 256 * 2;
  u16* wvt = (u16*)p; p += (size_t)256 * 256 * 2;
  u16* wpt = (u16*)p; p += (size_t)256 * 256 * 2;
  u16* aobuf = xn_b;  // xn_b dead after gemm_qkv

  ln_prep<<<dim3(4096, 2), 256, 0, stream>>>(inputs, context, gamma, beta, xn_f, xn_b, ctx_b);
  wtrans<<<dim3(16, 4), 256, 0, stream>>>(Wq, Wk, Wv, Wp, wqt, wkt, wvt, wpt);
  gemm_qkv<<<dim3(256, 3), 256, 0, stream>>>(xn_b, ctx_b, wqt, wkt, wvt, bq, bk, bv, qbuf, kbuf, vtbuf);
  attn_kernel<<<dim3(64, 4), 256, 0, stream>>>(qbuf, kbuf, vtbuf, aobuf);
  gemm_proj<<<dim3(256), 256, 0, stream>>>(aobuf, wpt, bp, xn_f, out);
}